// Round 13
// baseline (949.157 us; speedup 1.0000x reference)
//
#include <hip/hip_runtime.h>

#define NN      524288      // nodes
#define NE      2097152     // edges
#define NGRAPH  16384
#define GSZ     32
#define PADR    45
#define F_IN    79
#define F_MID   138
#define F_OUT   128

#define NSTR    256         // cursor stripes for counting sort
// table split: M = cols 0..63 (128B rows, line-aligned), S = cols 64..79 (32B rows)

typedef __attribute__((ext_vector_type(8))) short short8;
typedef __attribute__((ext_vector_type(4))) float f32x4;

__device__ __forceinline__ unsigned short f2b(float f) {
    union { float f; unsigned u; } v; v.f = f;
    unsigned r = v.u + 0x7FFF + ((v.u >> 16) & 1);   // RNE
    return (unsigned short)(r >> 16);
}
__device__ __forceinline__ float b2f(unsigned short u) {
    union { unsigned u; float f; } v; v.u = ((unsigned)u) << 16;
    return v.f;
}

// ---------------- init: cnt=1 (self loop) + zero hist ----------------

__global__ void k_init(int* __restrict__ cnt, int* __restrict__ hist2) {
    int i = blockIdx.x * 256 + threadIdx.x;
    if (i < NN) cnt[i] = 1;
    if (i < NSTR * 64) hist2[i] = 0;
}

__global__ void k_count(const int* __restrict__ dst, int* __restrict__ cnt) {
    int e = blockIdx.x * 256 + threadIdx.x;
    if (e < NE) atomicAdd(&cnt[dst[e]], 1);
}

// ---------------- degree-balanced permutation (striped counting sort, DESCENDING = LPT) ----------------

__global__ void k_hist2(const int* __restrict__ cnt, int* __restrict__ hist2) {
    int i = blockIdx.x * 256 + threadIdx.x;
    if (i < NN) {
        int d = min(cnt[i], 63);
        atomicAdd(&hist2[(blockIdx.x & (NSTR - 1)) * 64 + d], 1);
    }
}

// exclusive scan in rank order; rank = DESCENDING degree major, stripe minor (LPT)
__global__ void k_sscan(const int* __restrict__ hist2, int* __restrict__ cur) {
    __shared__ int sh[NSTR * 64];
    __shared__ int s[256];
    int t = threadIdx.x;
    for (int i = t; i < NSTR * 64; i += 256) sh[i] = hist2[i];
    __syncthreads();
    int sum = 0;
    for (int k = 0; k < 64; ++k) {
        int r = t * 64 + k;
        int d = 63 - (r >> 8), stripe = r & (NSTR - 1);
        sum += sh[stripe * 64 + d];
    }
    s[t] = sum;
    __syncthreads();
    for (int off = 1; off < 256; off <<= 1) {
        int u = (t >= off) ? s[t - off] : 0;
        __syncthreads();
        s[t] += u;
        __syncthreads();
    }
    int run = s[t] - sum;
    for (int k = 0; k < 64; ++k) {
        int r = t * 64 + k;
        int d = 63 - (r >> 8), stripe = r & (NSTR - 1);
        cur[stripe * 64 + d] = run;
        run += sh[stripe * 64 + d];
    }
}

__global__ void k_scatter2(const int* __restrict__ cnt, int* __restrict__ cur,
                           int* __restrict__ perm, int* __restrict__ ip,
                           float* __restrict__ dinvp, int* __restrict__ degp) {
    int i = blockIdx.x * 256 + threadIdx.x;
    if (i < NN) {
        int c = cnt[i];
        int d = min(c, 63);
        int pos = atomicAdd(&cur[(blockIdx.x & (NSTR - 1)) * 64 + d], 1);
        perm[pos] = i;
        ip[i] = pos;
        dinvp[pos] = rsqrtf((float)c);
        degp[pos] = c - 1;                       // edge count (no self loop)
    }
}

// ---------------- CSR over permuted rows (EDGES ONLY) ----------------

__global__ void k_scan1p(const int* __restrict__ degp, int* __restrict__ rp,
                         int* __restrict__ bsum) {
    __shared__ int s[256];
    int tid = threadIdx.x;
    size_t base = (size_t)blockIdx.x * 1024 + (size_t)tid * 4;
    int c0 = degp[base + 0], c1 = degp[base + 1];
    int c2 = degp[base + 2], c3 = degp[base + 3];
    int tsum = c0 + c1 + c2 + c3;
    s[tid] = tsum;
    __syncthreads();
    for (int off = 1; off < 256; off <<= 1) {
        int t = (tid >= off) ? s[tid - off] : 0;
        __syncthreads();
        s[tid] += t;
        __syncthreads();
    }
    int incl = s[tid];
    int ex = incl - tsum;
    rp[base + 0] = ex;
    rp[base + 1] = ex + c0;
    rp[base + 2] = ex + c0 + c1;
    rp[base + 3] = ex + c0 + c1 + c2;
    if (tid == 255) bsum[blockIdx.x] = incl;
}

__global__ void k_scan2(int* __restrict__ bsum) {
    __shared__ int s[512];
    int tid = threadIdx.x;
    int v = bsum[tid];
    s[tid] = v;
    __syncthreads();
    for (int off = 1; off < 512; off <<= 1) {
        int t = (tid >= off) ? s[tid - off] : 0;
        __syncthreads();
        s[tid] += t;
        __syncthreads();
    }
    bsum[tid] = s[tid] - v;                      // exclusive
}

__global__ void k_scan3(int* __restrict__ rp, const int* __restrict__ bsum,
                        int* __restrict__ cursor) {
    int i = blockIdx.x * 256 + threadIdx.x;
    if (i < NN) {
        int v = rp[i] + bsum[i >> 10];
        rp[i] = v;
        cursor[i] = v;
        if (i == 0) rp[NN] = NE;
    }
}

__global__ void k_fill_edges(const int* __restrict__ src, const int* __restrict__ dst,
                             const int* __restrict__ ip,
                             int* __restrict__ cursor, int* __restrict__ col) {
    int e = blockIdx.x * 256 + threadIdx.x;
    if (e < NE) {
        int r = ip[dst[e]], c = ip[src[e]];
        int s = atomicAdd(&cursor[r], 1);
        col[s] = c;
    }
}

// ---------------- composite weights ----------------
// C[M,N]=A*B + bias row: block m<M -> C[m,:]; block M -> cv = av·B
__global__ void k_mm2(const float* __restrict__ A, const float* __restrict__ av,
                      const float* __restrict__ B, float* __restrict__ C,
                      float* __restrict__ cv, int M, int K, int N) {
    int m = blockIdx.x, n = threadIdx.x;
    const float* ar = (m < M) ? (A + (size_t)m * K) : av;
    float s = 0.f;
    for (int k = 0; k < K; ++k) s += ar[k] * B[(size_t)k * N + n];
    if (m < M) C[(size_t)m * N + n] = s;
    else       cv[n] = s;
}

// stage 3: Wc = W1·Q2 (written transposed into WxT), bias row r1 = b1·Q2,
// plus fill WxT cols 79..95: [0, r3, r2, r1, b4, 0...]
__global__ void k_mm3(const float* __restrict__ W1, const float* __restrict__ b1,
                      const float* __restrict__ Q2, const float* __restrict__ r2,
                      const float* __restrict__ r3, const float* __restrict__ b4,
                      unsigned short* __restrict__ WxT) {
    int m = blockIdx.x, n = threadIdx.x;     // m: 0..79 (79 = bias row), n: 0..127
    const float* ar = (m < 79) ? (W1 + (size_t)m * 138) : b1;
    float s = 0.f;
    for (int k = 0; k < 138; ++k) s += ar[k] * Q2[(size_t)k * 128 + n];
    if (m < 79) {
        WxT[(size_t)n * 96 + m] = f2b(s);
    } else {
        unsigned short* w = WxT + (size_t)n * 96;
        w[79] = 0;
        w[80] = f2b(r3[n]);
        w[81] = f2b(r2[n]);
        w[82] = f2b(s);                      // r1
        w[83] = f2b(b4[n]);
        for (int k = 84; k < 96; ++k) w[k] = 0;
    }
}

// split tables: Hm[ip[n]][c] c<64 ; Hs[ip[n]][c-64] c=64..78 ; Hs col 15 = dinv
__global__ void k_xconv(const float* __restrict__ x, const int* __restrict__ ip,
                        const float* __restrict__ dinvp,
                        unsigned short* __restrict__ Hm, unsigned short* __restrict__ Hs) {
    int n = blockIdx.x * 4 + threadIdx.y;
    int c = threadIdx.x;            // 0..79
    int t = ip[n];
    float d = dinvp[t];
    float v = (c < F_IN) ? d * x[(size_t)n * F_IN + c] : d;
    unsigned short b = f2b(v);
    if (c < 64) Hm[(size_t)t * 64 + c] = b;
    else        Hs[(size_t)t * 16 + (c - 64)] = b;
}

// ---------------- gather helpers (split tables) ----------------

__device__ __forceinline__ void g_load(const unsigned short* __restrict__ Hm,
                                       const unsigned short* __restrict__ Hs,
                                       int j, int kg, short8 v[3]) {
    const unsigned short* m = Hm + (size_t)j * 64 + kg * 8;
    v[0] = *(const short8*)(m);
    v[1] = *(const short8*)(m + 32);
    if (kg < 2) v[2] = *(const short8*)(Hs + (size_t)j * 16 + kg * 8);
}

__device__ __forceinline__ void g_acc(float acc[3][8], const short8 v[3], int kg) {
#pragma unroll
    for (int e = 0; e < 8; ++e) acc[0][e] += b2f((unsigned short)v[0][e]);
#pragma unroll
    for (int e = 0; e < 8; ++e) acc[1][e] += b2f((unsigned short)v[1][e]);
    if (kg < 2) {
#pragma unroll
        for (int e = 0; e < 8; ++e) acc[2][e] += b2f((unsigned short)v[2][e]);
    }
}

// fully-staged batch of B edges: issue ALL loads, then accumulate
template<int B>
__device__ __forceinline__ void g_batch(const unsigned short* __restrict__ Hm,
                                        const unsigned short* __restrict__ Hs,
                                        const int* __restrict__ col, int s, int kg,
                                        float acc[3][8]) {
    int j[B];
#pragma unroll
    for (int q = 0; q < B; ++q) j[q] = col[s + q];
    short8 v[B][3];
#pragma unroll
    for (int q = 0; q < B; ++q) g_load(Hm, Hs, j[q], kg, v[q]);
#pragma unroll
    for (int q = 0; q < B; ++q) g_acc(acc, v[q], kg);
}

// batched edge gather; degree is wave-uniform (LPT) -> branches are coherent
__device__ __forceinline__ void g_edges(const unsigned short* __restrict__ Hm,
                                        const unsigned short* __restrict__ Hs,
                                        const int* __restrict__ col,
                                        int beg, int end, int kg, float acc[3][8]) {
    int s = beg;
    for (; s + 4 <= end; s += 4) g_batch<4>(Hm, Hs, col, s, kg, acc);
    int rem = end - s;
    if (rem == 3)      g_batch<3>(Hm, Hs, col, s, kg, acc);
    else if (rem == 2) g_batch<2>(Hm, Hs, col, s, kg, acc);
    else if (rem == 1) g_batch<1>(Hm, Hs, col, s, kg, acc);
}

// ---------------- pure aggregation: T_{k+1} = A T_k (split tables) ----------------
__global__ __launch_bounds__(256) void
k_agg_s(const unsigned short* __restrict__ Hm, const unsigned short* __restrict__ Hs,
        unsigned short* __restrict__ Om, unsigned short* __restrict__ Os,
        float* __restrict__ usnap,
        const int* __restrict__ rp, const int* __restrict__ col,
        const float* __restrict__ dinvp) {
    const int tid = threadIdx.x;
    const int wv = tid >> 6, lane = tid & 63;
    const int lrow = lane & 15, kg = lane >> 4;
    const int row = blockIdx.x * 64 + wv * 16 + lrow;
    const int beg = rp[row], end = rp[row + 1];

    short8 sv[3];
    g_load(Hm, Hs, row, kg, sv);                 // self row: issue first ...

    float acc[3][8];
#pragma unroll
    for (int ks = 0; ks < 3; ++ks)
#pragma unroll
        for (int e = 0; e < 8; ++e) acc[ks][e] = 0.f;

    g_edges(Hm, Hs, col, beg, end, kg, acc);
    g_acc(acc, sv, kg);                          // ... consume last

    const float di = dinvp[row];
    const float d2 = di * di;
    unsigned short* om = Om + (size_t)row * 64 + kg * 8;
#pragma unroll
    for (int ks = 0; ks < 2; ++ks) {
        short8 o;
#pragma unroll
        for (int e = 0; e < 8; ++e) o[e] = (short)f2b(d2 * acc[ks][e]);
        *(short8*)(om + ks * 32) = o;
    }
    if (kg < 2) {
        short8 o;
#pragma unroll
        for (int e = 0; e < 8; ++e) o[e] = (short)f2b(d2 * acc[2][e]);
        *(short8*)(Os + (size_t)row * 16 + kg * 8) = o;
        if (kg == 1) usnap[row] = di * acc[2][7];   // col-79 value = A^k 1
    }
}

// ---------------- fused 4th aggregation + final GEMM + pad-zero ----------------
__global__ __launch_bounds__(256) void
k_agg_out(const unsigned short* __restrict__ Hm, const unsigned short* __restrict__ Hs,
          const unsigned short* __restrict__ WxT,
          const float* __restrict__ u1, const float* __restrict__ u2,
          const float* __restrict__ u3, float* __restrict__ Yo,
          const int* __restrict__ rp, const int* __restrict__ col,
          const float* __restrict__ dinvp, const int* __restrict__ perm) {
    constexpr int ROWB = 192;                    // 96 cols * 2B
    __shared__ __align__(16) unsigned short Ws[128 * 96];

    const int tid = threadIdx.x;
    for (int i = tid; i < 128 * 96 / 8; i += 256) {
        int r = i / 12, cc = i % 12;
        int bo = cc * 16;
        int so = (bo < 128) ? (bo ^ ((r & 7) << 4)) : bo;
        *(f32x4*)((char*)Ws + (size_t)r * ROWB + so) =
            *(const f32x4*)&WxT[(size_t)r * 96 + cc * 8];
    }

    // ---- zero pad rows for graphs 2b, 2b+1 (fixed region, disjoint from data rows) ----
    {
        const f32x4 z = (f32x4){0.f, 0.f, 0.f, 0.f};
        size_t g0 = (size_t)blockIdx.x * 2;
        for (int i = tid; i < 2 * 13 * 32; i += 256) {   // 13 rows x 128 cols = 416 f32x4/graph
            int g = i / 416, rem = i % 416;
            float* dst = Yo + ((g0 + g) * PADR + GSZ) * (size_t)F_OUT + rem * 4;
            __builtin_nontemporal_store(z, (f32x4*)dst);
        }
    }

    const int wv = tid >> 6, lane = tid & 63;
    const int lrow = lane & 15, kg = lane >> 4;
    const int row = blockIdx.x * 64 + wv * 16 + lrow;
    const int beg = rp[row], end = rp[row + 1];

    float acc[3][8];
#pragma unroll
    for (int ks = 0; ks < 3; ++ks)
#pragma unroll
        for (int e = 0; e < 8; ++e) acc[ks][e] = 0.f;

    {   // self row first
        short8 sv[3];
        g_load(Hm, Hs, row, kg, sv);
        g_acc(acc, sv, kg);
    }
    g_edges(Hm, Hs, col, beg, end, kg, acc);

    // A-fragments: T4 row slice (bf16) + u columns
    const float di = dinvp[row];
    short8 a[3];
#pragma unroll
    for (int ks = 0; ks < 2; ++ks)
#pragma unroll
        for (int e = 0; e < 8; ++e) a[ks][e] = (short)f2b(di * acc[ks][e]);
    if (kg < 2) {
#pragma unroll
        for (int e = 0; e < 8; ++e) a[2][e] = (short)f2b(di * acc[2][e]);
    } else if (kg == 2) {
        a[2][0] = (short)f2b(u1[row]);
        a[2][1] = (short)f2b(u2[row]);
        a[2][2] = (short)f2b(u3[row]);
        a[2][3] = (short)0x3F80;                 // bf16(1.0)
#pragma unroll
        for (int e = 4; e < 8; ++e) a[2][e] = 0;
    } else {
#pragma unroll
        for (int e = 0; e < 8; ++e) a[2][e] = 0;
    }

    __syncthreads();

    f32x4 acc2[8];
#pragma unroll
    for (int n = 0; n < 8; ++n) acc2[n] = (f32x4){0.f, 0.f, 0.f, 0.f};

#pragma unroll
    for (int ks = 0; ks < 3; ++ks) {
        const int bo = ks * 64 + kg * 16;
#pragma unroll
        for (int n = 0; n < 8; ++n) {
            int r = n * 16 + lrow;
            int so = (bo < 128) ? (bo ^ ((r & 7) << 4)) : bo;
            short8 b = *(const short8*)((const char*)Ws + (size_t)r * ROWB + so);
            acc2[n] = __builtin_amdgcn_mfma_f32_16x16x32_bf16(a[ks], b, acc2[n], 0, 0, 0);
        }
    }

    const int t0 = blockIdx.x * 64 + wv * 16 + kg * 4;
    int pr[4];
#pragma unroll
    for (int j = 0; j < 4; ++j) pr[j] = perm[t0 + j];
#pragma unroll
    for (int n = 0; n < 8; ++n) {
        int c = n * 16 + lrow;
#pragma unroll
        for (int j = 0; j < 4; ++j) {
            size_t o = ((size_t)(pr[j] >> 5) * PADR + (pr[j] & 31)) * F_OUT + c;
            __builtin_nontemporal_store(acc2[n][j], &Yo[o]);
        }
    }
}

// ---------------- launch ----------------

static inline size_t align256(size_t x) { return (x + 255) & ~(size_t)255; }

extern "C" void kernel_launch(void* const* d_in, const int* in_sizes, int n_in,
                              void* d_out, int out_size, void* d_ws, size_t ws_size,
                              hipStream_t stream) {
    const float* x   = (const float*)d_in[0];
    const int* ei    = (const int*)d_in[1];
    const int* src   = ei;            // edge_index[0]
    const int* dst   = ei + NE;       // edge_index[1]
    const float* W1  = (const float*)d_in[2];
    const float* b1  = (const float*)d_in[3];
    const float* W2  = (const float*)d_in[4];
    const float* b2  = (const float*)d_in[5];
    const float* W3  = (const float*)d_in[6];
    const float* b3  = (const float*)d_in[7];
    const float* W4  = (const float*)d_in[8];
    const float* b4  = (const float*)d_in[9];

    // workspace layout
    char* p = (char*)d_ws;
    unsigned short* MA = (unsigned short*)p;  p += align256((size_t)NN * 64 * 2);
    unsigned short* SA = (unsigned short*)p;  p += align256((size_t)NN * 16 * 2);
    unsigned short* MB = (unsigned short*)p;  p += align256((size_t)NN * 64 * 2);
    unsigned short* SB = (unsigned short*)p;  p += align256((size_t)NN * 16 * 2);
    int* cnt    = (int*)p;              p += align256((size_t)NN * sizeof(int));
    int* rp     = (int*)p;              p += align256(((size_t)NN + 1) * sizeof(int));
    int* cursor = (int*)p;              p += align256((size_t)NN * sizeof(int));
    int* colix  = (int*)p;              p += align256((size_t)NE * sizeof(int));
    float* dinvp= (float*)p;            p += align256((size_t)NN * sizeof(float));
    int* perm   = (int*)p;              p += align256((size_t)NN * sizeof(int));
    int* ip     = (int*)p;              p += align256((size_t)NN * sizeof(int));
    int* degp   = (int*)p;              p += align256((size_t)NN * sizeof(int));
    int* hist2  = (int*)p;              p += align256((size_t)NSTR * 64 * sizeof(int));
    int* cur    = (int*)p;              p += align256((size_t)NSTR * 64 * sizeof(int));
    int* bsum   = (int*)p;              p += align256(512 * sizeof(int));
    float* u1   = (float*)p;            p += align256((size_t)NN * sizeof(float));
    float* u2   = (float*)p;            p += align256((size_t)NN * sizeof(float));
    float* u3   = (float*)p;            p += align256((size_t)NN * sizeof(float));
    float* P34  = (float*)p;            p += align256(138 * 128 * sizeof(float));
    float* Q2   = (float*)p;            p += align256(138 * 128 * sizeof(float));
    float* r2   = (float*)p;            p += align256(128 * sizeof(float));
    float* r3   = (float*)p;            p += align256(128 * sizeof(float));
    unsigned short* WxT = (unsigned short*)p; p += align256(128 * 96 * 2);
    (void)ws_size; (void)n_in; (void)in_sizes; (void)out_size;

    // T0 tables live in d_out scratch (read fully before agg_out writes d_out)
    unsigned short* M0 = (unsigned short*)d_out;
    unsigned short* S0 = (unsigned short*)((char*)d_out + align256((size_t)NN * 64 * 2));

    // ---- degree count + striped counting sort (descending = LPT) ----
    k_init<<<NN / 256, 256, 0, stream>>>(cnt, hist2);
    k_count<<<NE / 256, 256, 0, stream>>>(dst, cnt);
    k_hist2<<<NN / 256, 256, 0, stream>>>(cnt, hist2);
    k_sscan<<<1, 256, 0, stream>>>(hist2, cur);
    k_scatter2<<<NN / 256, 256, 0, stream>>>(cnt, cur, perm, ip, dinvp, degp);

    // ---- CSR in permuted space (edges only) ----
    k_scan1p<<<NN / 1024, 256, 0, stream>>>(degp, rp, bsum);
    k_scan2<<<1, 512, 0, stream>>>(bsum);
    k_scan3<<<NN / 256, 256, 0, stream>>>(rp, bsum, cursor);
    k_fill_edges<<<NE / 256, 256, 0, stream>>>(src, dst, ip, cursor, colix);

    // ---- composite weights: P=W3W4,r3=b3W4 ; Q=W2P,r2=b2P ; WxT = [W1Q | aux] ----
    k_mm2<<<139, 128, 0, stream>>>(W3, b3, W4, P34, r3, 138, 138, 128);
    k_mm2<<<139, 128, 0, stream>>>(W2, b2, P34, Q2, r2, 138, 138, 128);
    k_mm3<<<80, 128, 0, stream>>>(W1, b1, Q2, r2, r3, b4, WxT);

    // ---- input tables T0 (prescaled; S col 15 = dinv) ----
    {
        dim3 b(80, 4);
        k_xconv<<<NN / 4, b, 0, stream>>>(x, ip, dinvp, M0, S0);
    }

    const int blocks = NN / 64;   // 8192 (64 rows per 256-thread block)

    // ---- 3 pure aggregations + fused 4th+GEMM+padzero ----
    k_agg_s<<<blocks, 256, 0, stream>>>(M0, S0, MA, SA, u1, rp, colix, dinvp);
    k_agg_s<<<blocks, 256, 0, stream>>>(MA, SA, MB, SB, u2, rp, colix, dinvp);
    k_agg_s<<<blocks, 256, 0, stream>>>(MB, SB, MA, SA, u3, rp, colix, dinvp);
    k_agg_out<<<blocks, 256, 0, stream>>>(MA, SA, WxT, u1, u2, u3, (float*)d_out,
                                          rp, colix, dinvp, perm);
}